// Round 1
// baseline (760.776 us; speedup 1.0000x reference)
//
#include <hip/hip_runtime.h>
#include <math.h>

typedef float2 cplx;
#define PI_F 3.14159265358979323846f
#define C8F 0.70710678118654752440f

__device__ __forceinline__ cplx cadd(cplx a, cplx b){ return make_float2(a.x+b.x, a.y+b.y); }
__device__ __forceinline__ cplx csub(cplx a, cplx b){ return make_float2(a.x-b.x, a.y-b.y); }
__device__ __forceinline__ cplx cmul(cplx a, cplx b){ return make_float2(a.x*b.x - a.y*b.y, a.x*b.y + a.y*b.x); }
__device__ __forceinline__ cplx cmulc(cplx a, cplx b){ return make_float2(a.x*b.x + a.y*b.y, a.y*b.x - a.x*b.y); }
__device__ __forceinline__ cplx cax(float s, cplx v){ return make_float2(s*v.x, s*v.y); }

template<bool INV>
__device__ __forceinline__ void dft8(cplx* v) {
    cplx t0 = cadd(v[0], v[4]), u0 = csub(v[0], v[4]);
    cplx t1 = cadd(v[1], v[5]), u1 = csub(v[1], v[5]);
    cplx t2 = cadd(v[2], v[6]), u2 = csub(v[2], v[6]);
    cplx t3 = cadd(v[3], v[7]), u3 = csub(v[3], v[7]);
    if (!INV) {
        u1 = make_float2(C8F*(u1.x + u1.y), C8F*(u1.y - u1.x));
        u2 = make_float2(u2.y, -u2.x);
        u3 = make_float2(C8F*(u3.y - u3.x), -C8F*(u3.x + u3.y));
    } else {
        u1 = make_float2(C8F*(u1.x - u1.y), C8F*(u1.x + u1.y));
        u2 = make_float2(-u2.y, u2.x);
        u3 = make_float2(-C8F*(u3.x + u3.y), C8F*(u3.x - u3.y));
    }
    cplx b0 = cadd(t0,t2), b1 = cadd(t1,t3), b2 = csub(t0,t2), b3 = csub(t1,t3);
    b3 = INV ? make_float2(-b3.y, b3.x) : make_float2(b3.y, -b3.x);
    v[0] = cadd(b0,b1); v[4] = csub(b0,b1); v[2] = cadd(b2,b3); v[6] = csub(b2,b3);
    cplx c0 = cadd(u0,u2), c1 = cadd(u1,u3), c2 = csub(u0,u2), c3 = csub(u1,u3);
    c3 = INV ? make_float2(-c3.y, c3.x) : make_float2(c3.y, -c3.x);
    v[1] = cadd(c0,c1); v[5] = csub(c0,c1); v[3] = cadd(c2,c3); v[7] = csub(c2,c3);
}

template<bool INV>
__device__ __forceinline__ void dft4(cplx* v) {
    cplx b0 = cadd(v[0], v[2]), b2 = csub(v[0], v[2]);
    cplx b1 = cadd(v[1], v[3]), b3 = csub(v[1], v[3]);
    b3 = INV ? make_float2(-b3.y, b3.x) : make_float2(b3.y, -b3.x);
    v[0] = cadd(b0,b1); v[2] = csub(b0,b1); v[1] = cadd(b2,b3); v[3] = csub(b2,b3);
}

// 16-point DFT, natural in/out. X[c+4d] = sum_a W16^{ac} W4^{ad} (sum_b x[a+4b] W4^{bc})
template<bool INV>
__device__ __forceinline__ void dft16(cplx* v) {
    #pragma unroll
    for (int a = 0; a < 4; ++a) {
        cplx t[4] = { v[a], v[a+4], v[a+8], v[a+12] };
        dft4<INV>(t);
        v[a] = t[0]; v[a+4] = t[1]; v[a+8] = t[2]; v[a+12] = t[3];
    }
    const float C1 = 0.92387953251128674f, S1 = 0.38268343236508978f, R2 = 0.70710678118654752f;
    #define TWX(idx, CR, CI) v[idx] = cmul(v[idx], make_float2(CR, INV ? -(CI) : (CI)))
    TWX(1+4*1,  C1, -S1);   // W16^1
    TWX(1+4*2,  R2, -R2);   // W16^2
    TWX(1+4*3,  S1, -C1);   // W16^3
    TWX(2+4*1,  R2, -R2);   // W16^2
    TWX(2+4*2, 0.f, -1.f);  // W16^4
    TWX(2+4*3, -R2, -R2);   // W16^6
    TWX(3+4*1,  S1, -C1);   // W16^3
    TWX(3+4*2, -R2, -R2);   // W16^6
    TWX(3+4*3, -C1,  S1);   // W16^9
    #undef TWX
    cplx o[16];
    #pragma unroll
    for (int c = 0; c < 4; ++c) {
        cplx t[4] = { v[4*c+0], v[4*c+1], v[4*c+2], v[4*c+3] };
        dft4<INV>(t);
        o[c] = t[0]; o[c+4] = t[1]; o[c+8] = t[2]; o[c+12] = t[3];
    }
    #pragma unroll
    for (int i = 0; i < 16; ++i) v[i] = o[i];
}

// swizzled twiddle-table index (breaks bank collisions for strided products)
__device__ __forceinline__ int twp(int i){ return i + (i >> 4); }

// B: [512 t][256 h][128 w] cplx = 128 MiB (all of d_ws).
__host__ __device__ __forceinline__ size_t idxB(int t, int h, int w) {
    return ((size_t)t * 256 + h) * 128 + w;
}

// K0a: compact row m of (mtx * gridz^4) into <=16 (val,col) pairs (banded).
__global__ __launch_bounds__(256) void k0_mtx(
        const float* __restrict__ mtx, const float* __restrict__ gridz,
        float* __restrict__ tv, int* __restrict__ tc) {
    int m = blockIdx.x, t = threadIdx.x;
    __shared__ float rv[256];
    float g = gridz[t]; float g2 = g * g;
    rv[t] = mtx[m * 256 + t] * (g2 * g2);
    __syncthreads();
    if (t == 0) {
        int cnt = 0;
        for (int k = 0; k < 256 && cnt < 16; ++k)
            if (rv[k] != 0.f) { tv[m*16 + cnt] = rv[k]; tc[m*16 + cnt] = k; ++cnt; }
        for (; cnt < 16; ++cnt) { tv[m*16 + cnt] = 0.f; tc[m*16 + cnt] = 0; }
    }
}

// K0b: compact row m of mtxi into <=8 (val,col) pairs.
// The global ifft normalization 1/(512*256*256) = 2^-25 is folded in here
// (moved out of k4, where it cost 32 v_mul per thread per pass).
__global__ __launch_bounds__(256) void k0_mtxi(
        const float* __restrict__ mtxi, float* __restrict__ tv, int* __restrict__ tc) {
    int m = blockIdx.x, t = threadIdx.x;
    const float S = 2.9802322387695312e-08f; // 1/2^25, exact
    __shared__ float rv[256];
    rv[t] = mtxi[m * 256 + t];
    __syncthreads();
    if (t == 0) {
        int cnt = 0;
        for (int k = 0; k < 256 && cnt < 8; ++k)
            if (rv[k] != 0.f) { tv[m*8 + cnt] = rv[k] * S; tc[m*8 + cnt] = k; ++cnt; }
        for (; cnt < 8; ++cnt) { tv[m*8 + cnt] = 0.f; tc[m*8 + cnt] = 0; }
    }
}

// K2': fused resample + forward 512-FFT along t. Reads feat, writes B[all t, h<128].
__global__ __launch_bounds__(512, 2) void k2_fftt(
        const float* __restrict__ feat, const float* __restrict__ tv,
        const int* __restrict__ tc, cplx* __restrict__ B) {
    const int h = blockIdx.x, w0 = blockIdx.y * 16;
    const int tid = threadIdx.x, ww = tid & 15, q = tid >> 4; // q in [0,32)
    __shared__ cplx buf[512 * 17];
    __shared__ cplx tw[512];
    { float s, c; sincosf(-(2.0f*PI_F/512.0f)*(float)tid, &s, &c); tw[tid] = make_float2(c, s); }
    // stage feat (both channels packed re+i*im) into LDS: f2[t*16+ww], t<256
    cplx* f2 = buf;
    for (int idx = tid; idx < 4096; idx += 512) {
        int t = idx >> 4, w = idx & 15;
        size_t o = ((size_t)t * 128 + h) * 128 + w0 + w;
        f2[idx] = make_float2(feat[o], feat[o + 4194304]);
    }
    __syncthreads();
    // sparse matvec: A[m] = sum_j val[m,j] * f2[col[m,j]]  (table broadcast across ww)
    cplx xa[2][8];
    for (int hi = 0; hi < 2; ++hi) {
        int u = q + 32*hi;
        #pragma unroll
        for (int p = 0; p < 8; ++p) {
            if (p < 4) {
                int m = u + 64*p;
                cplx acc = make_float2(0.f, 0.f);
                const float4* v4 = (const float4*)(tv + m*16);
                const int4*  c4 = (const int4*)(tc + m*16);
                #pragma unroll
                for (int jj = 0; jj < 4; ++jj) {
                    float4 vv = v4[jj]; int4 cc = c4[jj];
                    acc = cadd(acc, cax(vv.x, f2[cc.x*16 + ww]));
                    acc = cadd(acc, cax(vv.y, f2[cc.y*16 + ww]));
                    acc = cadd(acc, cax(vv.z, f2[cc.z*16 + ww]));
                    acc = cadd(acc, cax(vv.w, f2[cc.w*16 + ww]));
                }
                xa[hi][p] = acc;
            } else xa[hi][p] = make_float2(0.f, 0.f);
        }
    }
    dft8<false>(xa[0]); dft8<false>(xa[1]);
    __syncthreads();   // all f2 reads done before stage-A overwrites
    for (int hi = 0; hi < 2; ++hi) {
        int u = q + 32*hi;
        #pragma unroll
        for (int r = 1; r < 8; ++r) xa[hi][r] = cmul(xa[hi][r], tw[u * r]);
        #pragma unroll
        for (int r = 0; r < 8; ++r) buf[(64*r + u) * 17 + ww] = xa[hi][r];
    }
    __syncthreads();
    for (int hi = 0; hi < 2; ++hi) {
        int u = q + 32*hi, r1 = u >> 3, j = u & 7, base = 64*r1 + j;
        cplx y[8];
        #pragma unroll
        for (int p = 0; p < 8; ++p) y[p] = buf[(base + 8*p) * 17 + ww];
        dft8<false>(y);
        #pragma unroll
        for (int r2 = 1; r2 < 8; ++r2) y[r2] = cmul(y[r2], tw[8 * j * r2]);
        #pragma unroll
        for (int r2 = 0; r2 < 8; ++r2) buf[(base + 8*r2) * 17 + ww] = y[r2];
    }
    __syncthreads();
    for (int hi = 0; hi < 2; ++hi) {
        int m = q + 32*hi;
        cplx z[8];
        #pragma unroll
        for (int r = 0; r < 8; ++r) z[r] = buf[(8*m + r) * 17 + ww];
        dft8<false>(z);
        int kb = (m >> 3) + 8 * (m & 7);
        #pragma unroll
        for (int s2 = 0; s2 < 8; ++s2)
            B[idxB(kb + 64*s2, h, w0 + ww)] = z[s2];
    }
}

// K3: forward 256-FFT along h, radix-16^2, 1 LDS exchange. Reads h<128, writes all h.
__global__ __launch_bounds__(256) void k3_ffth(cplx* __restrict__ B) {
    const int t = blockIdx.x, w0 = blockIdx.y * 16;
    const int tid = threadIdx.x, ww = tid & 15, q = tid >> 4; // q in [0,16)
    __shared__ cplx buf[256 * 16];
    __shared__ cplx tw[272];
    { float s, c; sincosf(-(2.0f*PI_F/256.0f)*(float)tid, &s, &c); tw[twp(tid)] = make_float2(c, s); }
    cplx x[16];
    #pragma unroll
    for (int n2 = 0; n2 < 8; ++n2) x[n2] = B[idxB(t, q + 16*n2, w0 + ww)];
    #pragma unroll
    for (int n2 = 8; n2 < 16; ++n2) x[n2] = make_float2(0.f, 0.f);
    dft16<false>(x);                 // over n2 -> k2
    __syncthreads();                 // tw ready
    #pragma unroll
    for (int k2 = 1; k2 < 16; ++k2) x[k2] = cmul(x[k2], tw[twp(q * k2)]);
    #pragma unroll
    for (int k2 = 0; k2 < 16; ++k2) buf[(q + 16*k2) * 16 + ww] = x[k2];
    __syncthreads();
    cplx z[16];
    #pragma unroll
    for (int n1 = 0; n1 < 16; ++n1) z[n1] = buf[(n1 + 16*q) * 16 + ww];
    dft16<false>(z);                 // over n1 -> k1; h = q + 16*k1
    #pragma unroll
    for (int k1 = 0; k1 < 16; ++k1) B[idxB(t, q + 16*k1, w0 + ww)] = z[k1];
}

// K4 pass: one plane-line set: read w<128 -> fwd 256 FFT -> psf multiply (regs) ->
// inv 256 FFT -> write w<128. REV=true uses the Hermitian mirror of the psf line:
// invpsf[512-kt, 256-kh, kw] = conj(invpsf[kt, kh, (256-kw)%256]) (psf is real),
// so pass B re-reads the SAME psf addresses as pass A (L1/L2 hit, no HBM refetch).
template<bool REV>
__device__ __forceinline__ void k4_pass(
        cplx* __restrict__ B, const float* __restrict__ pr, const float* __restrict__ pim,
        size_t lineB, size_t lineP, int q, int l, cplx* buf, const cplx* tw, const cplx* xin) {
    cplx x[16];
    #pragma unroll
    for (int n2 = 0; n2 < 8; ++n2) x[n2] = xin[n2];
    #pragma unroll
    for (int n2 = 8; n2 < 16; ++n2) x[n2] = make_float2(0.f, 0.f);
    float prv[16], piv[16];
    #pragma unroll
    for (int k1 = 0; k1 < 16; ++k1) {
        int ip = REV ? ((256 - (q + 16*k1)) & 255) : (q + 16*k1);
        prv[k1] = pr[lineP + ip];
        piv[k1] = pim[lineP + ip];
    }
    dft16<false>(x);                 // over n2 -> k2
    #pragma unroll
    for (int k2 = 1; k2 < 16; ++k2) x[k2] = cmul(x[k2], tw[twp(q * k2)]);
    #pragma unroll
    for (int k2 = 0; k2 < 16; ++k2) buf[l*256 + (q ^ k2) + 16*k2] = x[k2];
    __syncthreads();
    cplx z[16];
    #pragma unroll
    for (int n1 = 0; n1 < 16; ++n1) z[n1] = buf[l*256 + (n1 ^ q) + 16*q];
    dft16<false>(z);                 // z[k1] = X[q + 16*k1]
    #pragma unroll
    for (int k1 = 0; k1 < 16; ++k1) {
        cplx p = make_float2(prv[k1], piv[k1]);
        z[k1] = REV ? cmulc(z[k1], p) : cmul(z[k1], p);   // REV: multiply by conj
    }
    dft16<true>(z);                  // inverse over k1 -> n1
    #pragma unroll
    for (int n1 = 1; n1 < 16; ++n1) z[n1] = cmulc(z[n1], tw[twp(n1 * q)]);
    #pragma unroll
    for (int n1 = 0; n1 < 16; ++n1) buf[l*256 + (n1 ^ q) + 16*q] = z[n1]; // own column
    __syncthreads();
    cplx y[16];
    #pragma unroll
    for (int k2 = 0; k2 < 16; ++k2) y[k2] = buf[l*256 + (q ^ k2) + 16*k2];
    dft16<true>(y);                  // over k2 -> n2; w = q + 16*n2
    #pragma unroll
    for (int n2 = 0; n2 < 8; ++n2) B[lineB + q + 16*n2] = y[n2];
}

// K4: fused w-pass with Hermitian psf pairing. Block bx<255 handles plane kt=bx+1
// (psf read from HBM) AND plane 512-kt with mirrored kh lines (psf = conj reversed
// re-read of the same lines -> cache hit). Block bx==255 handles the two
// self-conjugate planes 0 and 256 directly. psf HBM fetch: 268 MB -> ~134 MB.
__global__ __launch_bounds__(256, 4) void k4_fftw(
        cplx* __restrict__ B, const float* __restrict__ pr, const float* __restrict__ pim) {
    const int bx = blockIdx.x, kh0 = blockIdx.y * 16;
    const int tid = threadIdx.x, q = tid & 15, l = tid >> 4; // q fast for w-coalescing
    __shared__ cplx buf[16 * 256];
    __shared__ cplx tw[272];
    { float s, c; sincosf(-(2.0f*PI_F/256.0f)*(float)tid, &s, &c); tw[twp(tid)] = make_float2(c, s); }
    const bool last = (bx == 255);
    const int ktA = last ? 0 : bx + 1;           // planes 1..255, and 0
    const int khA = kh0 + l;
    const int ktB = last ? 256 : 512 - ktA;      // planes 257..511, and 256
    const int khB = last ? khA : ((256 - khA) & 255);
    const size_t lineBA = idxB(ktA, khA, 0);
    const size_t lineBB = idxB(ktB, khB, 0);
    const size_t linePA = ((size_t)ktA * 256 + khA) * 256;
    const size_t linePB = last ? (((size_t)256 * 256 + khA) * 256) : linePA;
    cplx xA[8], xB[8];
    #pragma unroll
    for (int n2 = 0; n2 < 8; ++n2) xA[n2] = B[lineBA + q + 16*n2];
    #pragma unroll
    for (int n2 = 0; n2 < 8; ++n2) xB[n2] = B[lineBB + q + 16*n2]; // prefetch pass B
    __syncthreads();                             // tw ready
    k4_pass<false>(B, pr, pim, lineBA, linePA, q, l, buf, tw, xA);
    __syncthreads();                             // pass-A buf reads complete
    if (last) k4_pass<false>(B, pr, pim, lineBB, linePB, q, l, buf, tw, xB);
    else      k4_pass<true >(B, pr, pim, lineBB, linePB, q, l, buf, tw, xB);
}

// K5: inverse 256-FFT along h, radix-16^2. Reads all h (natural freq), writes h<128.
__global__ __launch_bounds__(256) void k5_iffth(cplx* __restrict__ B) {
    const int t = blockIdx.x, w0 = blockIdx.y * 16;
    const int tid = threadIdx.x, ww = tid & 15, q = tid >> 4;
    __shared__ cplx buf[256 * 16];
    __shared__ cplx tw[272];
    { float s, c; sincosf(-(2.0f*PI_F/256.0f)*(float)tid, &s, &c); tw[twp(tid)] = make_float2(c, s); }
    cplx x[16];
    #pragma unroll
    for (int k1 = 0; k1 < 16; ++k1) x[k1] = B[idxB(t, q + 16*k1, w0 + ww)]; // q = k2
    dft16<true>(x);                  // over k1 -> n1
    __syncthreads();
    #pragma unroll
    for (int n1 = 1; n1 < 16; ++n1) x[n1] = cmulc(x[n1], tw[twp(n1 * q)]);
    #pragma unroll
    for (int n1 = 0; n1 < 16; ++n1) buf[(n1 + 16*q) * 16 + ww] = x[n1];
    __syncthreads();
    cplx z[16];
    #pragma unroll
    for (int k2 = 0; k2 < 16; ++k2) z[k2] = buf[(q + 16*k2) * 16 + ww]; // q = n1
    dft16<true>(z);                  // over k2 -> n2; h = q + 16*n2
    #pragma unroll
    for (int n2 = 0; n2 < 8; ++n2) B[idxB(t, q + 16*n2, w0 + ww)] = z[n2];
}

// K6': inverse 512-FFT along t fused with mtxi output matvec. Writes d_out only.
__global__ __launch_bounds__(512, 2) void k6_ifftt(
        cplx* __restrict__ B, const float* __restrict__ tv, const int* __restrict__ tc,
        float* __restrict__ out) {
    const int h = blockIdx.x, w0 = blockIdx.y * 16;
    const int tid = threadIdx.x, ww = tid & 15, q = tid >> 4; // q in [0,32)
    __shared__ cplx buf[512 * 17];
    __shared__ cplx tw[512];
    { float s, c; sincosf(-(2.0f*PI_F/512.0f)*(float)tid, &s, &c); tw[tid] = make_float2(c, s); }
    cplx za[2][8];
    for (int hi = 0; hi < 2; ++hi) {
        int m = q + 32*hi, kb = (m >> 3) + 8 * (m & 7);
        #pragma unroll
        for (int s2 = 0; s2 < 8; ++s2) za[hi][s2] = B[idxB(kb + 64*s2, h, w0 + ww)];
    }
    for (int hi = 0; hi < 2; ++hi) {
        int m = q + 32*hi;
        dft8<true>(za[hi]);
        #pragma unroll
        for (int jj = 0; jj < 8; ++jj) buf[(8*m + jj) * 17 + ww] = za[hi][jj];
    }
    __syncthreads();   // covers tw + buf
    for (int hi = 0; hi < 2; ++hi) {
        int u = q + 32*hi, r1 = u >> 3, j = u & 7, base = 64*r1 + j;
        cplx y[8];
        #pragma unroll
        for (int r2 = 0; r2 < 8; ++r2) y[r2] = buf[(base + 8*r2) * 17 + ww];
        #pragma unroll
        for (int r2 = 1; r2 < 8; ++r2) y[r2] = cmulc(y[r2], tw[8 * j * r2]);
        dft8<true>(y);
        #pragma unroll
        for (int p = 0; p < 8; ++p) buf[(base + 8*p) * 17 + ww] = y[p];
    }
    __syncthreads();
    cplx vol[2][4];
    for (int hi = 0; hi < 2; ++hi) {
        int u = q + 32*hi;
        cplx xo[8];
        #pragma unroll
        for (int r = 0; r < 8; ++r) xo[r] = buf[(64*r + u) * 17 + ww];
        #pragma unroll
        for (int r = 1; r < 8; ++r) xo[r] = cmulc(xo[r], tw[u * r]);
        dft8<true>(xo);
        #pragma unroll
        for (int p = 0; p < 4; ++p) vol[hi][p] = xo[p];  // t = u + 64p < 256
    }
    __syncthreads();   // all buf reads done before vol overwrite
    for (int hi = 0; hi < 2; ++hi) {
        int u = q + 32*hi;
        #pragma unroll
        for (int p = 0; p < 4; ++p) buf[(u + 64*p) * 16 + ww] = vol[hi][p];
    }
    __syncthreads();
    // out[m] = sum_j val[m,j] * vol[col[m,j]]  (table broadcast across ww)
    for (int hi = 0; hi < 2; ++hi) {
        int u = q + 32*hi;
        #pragma unroll
        for (int p = 0; p < 4; ++p) {
            int m = u + 64*p;
            cplx acc = make_float2(0.f, 0.f);
            const float4* v4 = (const float4*)(tv + m*8);
            const int4*  c4 = (const int4*)(tc + m*8);
            #pragma unroll
            for (int jj = 0; jj < 2; ++jj) {
                float4 vv = v4[jj]; int4 cc = c4[jj];
                acc = cadd(acc, cax(vv.x, buf[cc.x*16 + ww]));
                acc = cadd(acc, cax(vv.y, buf[cc.y*16 + ww]));
                acc = cadd(acc, cax(vv.z, buf[cc.z*16 + ww]));
                acc = cadd(acc, cax(vv.w, buf[cc.w*16 + ww]));
            }
            out[((size_t)m * 128 + h) * 128 + w0 + ww] = acc.x;
            out[(((size_t)256 + m) * 128 + h) * 128 + w0 + ww] = acc.y;
        }
    }
}

extern "C" void kernel_launch(void* const* d_in, const int* in_sizes, int n_in,
                              void* d_out, int out_size, void* d_ws, size_t ws_size,
                              hipStream_t stream) {
    const float* feat  = (const float*)d_in[0];
    const float* gridz = (const float*)d_in[1];
    const float* mtx   = (const float*)d_in[2];
    const float* mtxi  = (const float*)d_in[3];
    const float* pr    = (const float*)d_in[4];
    const float* pim   = (const float*)d_in[5];
    cplx* B = (cplx*)d_ws; // 512*256*128*8 = 128 MiB
    float* out = (float*)d_out;

    // mtx table in dead region [t=257, h>=128] (dead until k3 writes; consumed by k2')
    float* T1v = (float*)(B + idxB(257, 128, 0));
    int*   T1c = (int*)(T1v + 4096);
    // mtxi table in dead region [t=0, h>=128] (built after k5; consumed by k6')
    float* T2v = (float*)(B + idxB(0, 128, 0));
    int*   T2c = (int*)(T2v + 2048);

    k0_mtx <<<256, 256, 0, stream>>>(mtx, gridz, T1v, T1c);
    k2_fftt<<<dim3(128, 8), 512, 0, stream>>>(feat, T1v, T1c, B);
    k3_ffth<<<dim3(512, 8), 256, 0, stream>>>(B);
    k4_fftw<<<dim3(256, 16), 256, 0, stream>>>(B, pr, pim);
    k5_iffth<<<dim3(512, 8), 256, 0, stream>>>(B);
    k0_mtxi<<<256, 256, 0, stream>>>(mtxi, T2v, T2c);
    k6_ifftt<<<dim3(128, 8), 512, 0, stream>>>(B, T2v, T2c, out);
}

// Round 2
// 496.003 us; speedup vs baseline: 1.5338x; 1.5338x over previous
//
#include <hip/hip_runtime.h>
#include <math.h>

typedef float2 cplx;
#define PI_F 3.14159265358979323846f
#define C8F 0.70710678118654752440f

__device__ __forceinline__ cplx cadd(cplx a, cplx b){ return make_float2(a.x+b.x, a.y+b.y); }
__device__ __forceinline__ cplx csub(cplx a, cplx b){ return make_float2(a.x-b.x, a.y-b.y); }
__device__ __forceinline__ cplx cmul(cplx a, cplx b){ return make_float2(a.x*b.x - a.y*b.y, a.x*b.y + a.y*b.x); }
__device__ __forceinline__ cplx cmulc(cplx a, cplx b){ return make_float2(a.x*b.x + a.y*b.y, a.y*b.x - a.x*b.y); }
__device__ __forceinline__ cplx cax(float s, cplx v){ return make_float2(s*v.x, s*v.y); }

template<bool INV>
__device__ __forceinline__ void dft8(cplx* v) {
    cplx t0 = cadd(v[0], v[4]), u0 = csub(v[0], v[4]);
    cplx t1 = cadd(v[1], v[5]), u1 = csub(v[1], v[5]);
    cplx t2 = cadd(v[2], v[6]), u2 = csub(v[2], v[6]);
    cplx t3 = cadd(v[3], v[7]), u3 = csub(v[3], v[7]);
    if (!INV) {
        u1 = make_float2(C8F*(u1.x + u1.y), C8F*(u1.y - u1.x));
        u2 = make_float2(u2.y, -u2.x);
        u3 = make_float2(C8F*(u3.y - u3.x), -C8F*(u3.x + u3.y));
    } else {
        u1 = make_float2(C8F*(u1.x - u1.y), C8F*(u1.x + u1.y));
        u2 = make_float2(-u2.y, u2.x);
        u3 = make_float2(-C8F*(u3.x + u3.y), C8F*(u3.x - u3.y));
    }
    cplx b0 = cadd(t0,t2), b1 = cadd(t1,t3), b2 = csub(t0,t2), b3 = csub(t1,t3);
    b3 = INV ? make_float2(-b3.y, b3.x) : make_float2(b3.y, -b3.x);
    v[0] = cadd(b0,b1); v[4] = csub(b0,b1); v[2] = cadd(b2,b3); v[6] = csub(b2,b3);
    cplx c0 = cadd(u0,u2), c1 = cadd(u1,u3), c2 = csub(u0,u2), c3 = csub(u1,u3);
    c3 = INV ? make_float2(-c3.y, c3.x) : make_float2(c3.y, -c3.x);
    v[1] = cadd(c0,c1); v[5] = csub(c0,c1); v[3] = cadd(c2,c3); v[7] = csub(c2,c3);
}

template<bool INV>
__device__ __forceinline__ void dft4(cplx* v) {
    cplx b0 = cadd(v[0], v[2]), b2 = csub(v[0], v[2]);
    cplx b1 = cadd(v[1], v[3]), b3 = csub(v[1], v[3]);
    b3 = INV ? make_float2(-b3.y, b3.x) : make_float2(b3.y, -b3.x);
    v[0] = cadd(b0,b1); v[2] = csub(b0,b1); v[1] = cadd(b2,b3); v[3] = csub(b2,b3);
}

// 16-point DFT, natural in/out. X[c+4d] = sum_a W16^{ac} W4^{ad} (sum_b x[a+4b] W4^{bc})
template<bool INV>
__device__ __forceinline__ void dft16(cplx* v) {
    #pragma unroll
    for (int a = 0; a < 4; ++a) {
        cplx t[4] = { v[a], v[a+4], v[a+8], v[a+12] };
        dft4<INV>(t);
        v[a] = t[0]; v[a+4] = t[1]; v[a+8] = t[2]; v[a+12] = t[3];
    }
    const float C1 = 0.92387953251128674f, S1 = 0.38268343236508978f, R2 = 0.70710678118654752f;
    #define TWX(idx, CR, CI) v[idx] = cmul(v[idx], make_float2(CR, INV ? -(CI) : (CI)))
    TWX(1+4*1,  C1, -S1);   // W16^1
    TWX(1+4*2,  R2, -R2);   // W16^2
    TWX(1+4*3,  S1, -C1);   // W16^3
    TWX(2+4*1,  R2, -R2);   // W16^2
    TWX(2+4*2, 0.f, -1.f);  // W16^4
    TWX(2+4*3, -R2, -R2);   // W16^6
    TWX(3+4*1,  S1, -C1);   // W16^3
    TWX(3+4*2, -R2, -R2);   // W16^6
    TWX(3+4*3, -C1,  S1);   // W16^9
    #undef TWX
    cplx o[16];
    #pragma unroll
    for (int c = 0; c < 4; ++c) {
        cplx t[4] = { v[4*c+0], v[4*c+1], v[4*c+2], v[4*c+3] };
        dft4<INV>(t);
        o[c] = t[0]; o[c+4] = t[1]; o[c+8] = t[2]; o[c+12] = t[3];
    }
    #pragma unroll
    for (int i = 0; i < 16; ++i) v[i] = o[i];
}

// swizzled twiddle-table index (breaks bank collisions for strided products)
__device__ __forceinline__ int twp(int i){ return i + (i >> 4); }

// B: [512 t][256 h][128 w] cplx = 128 MiB (all of d_ws).
__host__ __device__ __forceinline__ size_t idxB(int t, int h, int w) {
    return ((size_t)t * 256 + h) * 128 + w;
}

// K0a: compact row m of (mtx * gridz^4) into <=16 (val,col) pairs (banded).
__global__ __launch_bounds__(256) void k0_mtx(
        const float* __restrict__ mtx, const float* __restrict__ gridz,
        float* __restrict__ tv, int* __restrict__ tc) {
    int m = blockIdx.x, t = threadIdx.x;
    __shared__ float rv[256];
    float g = gridz[t]; float g2 = g * g;
    rv[t] = mtx[m * 256 + t] * (g2 * g2);
    __syncthreads();
    if (t == 0) {
        int cnt = 0;
        for (int k = 0; k < 256 && cnt < 16; ++k)
            if (rv[k] != 0.f) { tv[m*16 + cnt] = rv[k]; tc[m*16 + cnt] = k; ++cnt; }
        for (; cnt < 16; ++cnt) { tv[m*16 + cnt] = 0.f; tc[m*16 + cnt] = 0; }
    }
}

// K0b: compact row m of mtxi into <=8 (val,col) pairs.
// The global ifft normalization 1/(512*256*256) = 2^-25 is folded in here
// (verified correct in a prior round; keeps 32 v_mul/thread out of k4).
__global__ __launch_bounds__(256) void k0_mtxi(
        const float* __restrict__ mtxi, float* __restrict__ tv, int* __restrict__ tc) {
    int m = blockIdx.x, t = threadIdx.x;
    const float S = 2.9802322387695312e-08f; // 1/2^25, exact
    __shared__ float rv[256];
    rv[t] = mtxi[m * 256 + t];
    __syncthreads();
    if (t == 0) {
        int cnt = 0;
        for (int k = 0; k < 256 && cnt < 8; ++k)
            if (rv[k] != 0.f) { tv[m*8 + cnt] = rv[k] * S; tc[m*8 + cnt] = k; ++cnt; }
        for (; cnt < 8; ++cnt) { tv[m*8 + cnt] = 0.f; tc[m*8 + cnt] = 0; }
    }
}

// K2': fused resample + forward 512-FFT along t. Reads feat, writes B[all t, h<128].
__global__ __launch_bounds__(512, 2) void k2_fftt(
        const float* __restrict__ feat, const float* __restrict__ tv,
        const int* __restrict__ tc, cplx* __restrict__ B) {
    const int h = blockIdx.x, w0 = blockIdx.y * 16;
    const int tid = threadIdx.x, ww = tid & 15, q = tid >> 4; // q in [0,32)
    __shared__ cplx buf[512 * 17];
    __shared__ cplx tw[512];
    { float s, c; sincosf(-(2.0f*PI_F/512.0f)*(float)tid, &s, &c); tw[tid] = make_float2(c, s); }
    // stage feat (both channels packed re+i*im) into LDS: f2[t*16+ww], t<256
    cplx* f2 = buf;
    for (int idx = tid; idx < 4096; idx += 512) {
        int t = idx >> 4, w = idx & 15;
        size_t o = ((size_t)t * 128 + h) * 128 + w0 + w;
        f2[idx] = make_float2(feat[o], feat[o + 4194304]);
    }
    __syncthreads();
    // sparse matvec: A[m] = sum_j val[m,j] * f2[col[m,j]]  (table broadcast across ww)
    cplx xa[2][8];
    for (int hi = 0; hi < 2; ++hi) {
        int u = q + 32*hi;
        #pragma unroll
        for (int p = 0; p < 8; ++p) {
            if (p < 4) {
                int m = u + 64*p;
                cplx acc = make_float2(0.f, 0.f);
                const float4* v4 = (const float4*)(tv + m*16);
                const int4*  c4 = (const int4*)(tc + m*16);
                #pragma unroll
                for (int jj = 0; jj < 4; ++jj) {
                    float4 vv = v4[jj]; int4 cc = c4[jj];
                    acc = cadd(acc, cax(vv.x, f2[cc.x*16 + ww]));
                    acc = cadd(acc, cax(vv.y, f2[cc.y*16 + ww]));
                    acc = cadd(acc, cax(vv.z, f2[cc.z*16 + ww]));
                    acc = cadd(acc, cax(vv.w, f2[cc.w*16 + ww]));
                }
                xa[hi][p] = acc;
            } else xa[hi][p] = make_float2(0.f, 0.f);
        }
    }
    dft8<false>(xa[0]); dft8<false>(xa[1]);
    __syncthreads();   // all f2 reads done before stage-A overwrites
    for (int hi = 0; hi < 2; ++hi) {
        int u = q + 32*hi;
        #pragma unroll
        for (int r = 1; r < 8; ++r) xa[hi][r] = cmul(xa[hi][r], tw[u * r]);
        #pragma unroll
        for (int r = 0; r < 8; ++r) buf[(64*r + u) * 17 + ww] = xa[hi][r];
    }
    __syncthreads();
    for (int hi = 0; hi < 2; ++hi) {
        int u = q + 32*hi, r1 = u >> 3, j = u & 7, base = 64*r1 + j;
        cplx y[8];
        #pragma unroll
        for (int p = 0; p < 8; ++p) y[p] = buf[(base + 8*p) * 17 + ww];
        dft8<false>(y);
        #pragma unroll
        for (int r2 = 1; r2 < 8; ++r2) y[r2] = cmul(y[r2], tw[8 * j * r2]);
        #pragma unroll
        for (int r2 = 0; r2 < 8; ++r2) buf[(base + 8*r2) * 17 + ww] = y[r2];
    }
    __syncthreads();
    for (int hi = 0; hi < 2; ++hi) {
        int m = q + 32*hi;
        cplx z[8];
        #pragma unroll
        for (int r = 0; r < 8; ++r) z[r] = buf[(8*m + r) * 17 + ww];
        dft8<false>(z);
        int kb = (m >> 3) + 8 * (m & 7);
        #pragma unroll
        for (int s2 = 0; s2 < 8; ++s2)
            B[idxB(kb + 64*s2, h, w0 + ww)] = z[s2];
    }
}

// K3: forward 256-FFT along h, radix-16^2, 1 LDS exchange. Reads h<128, writes all h.
__global__ __launch_bounds__(256) void k3_ffth(cplx* __restrict__ B) {
    const int t = blockIdx.x, w0 = blockIdx.y * 16;
    const int tid = threadIdx.x, ww = tid & 15, q = tid >> 4; // q in [0,16)
    __shared__ cplx buf[256 * 16];
    __shared__ cplx tw[272];
    { float s, c; sincosf(-(2.0f*PI_F/256.0f)*(float)tid, &s, &c); tw[twp(tid)] = make_float2(c, s); }
    cplx x[16];
    #pragma unroll
    for (int n2 = 0; n2 < 8; ++n2) x[n2] = B[idxB(t, q + 16*n2, w0 + ww)];
    #pragma unroll
    for (int n2 = 8; n2 < 16; ++n2) x[n2] = make_float2(0.f, 0.f);
    dft16<false>(x);                 // over n2 -> k2
    __syncthreads();                 // tw ready
    #pragma unroll
    for (int k2 = 1; k2 < 16; ++k2) x[k2] = cmul(x[k2], tw[twp(q * k2)]);
    #pragma unroll
    for (int k2 = 0; k2 < 16; ++k2) buf[(q + 16*k2) * 16 + ww] = x[k2];
    __syncthreads();
    cplx z[16];
    #pragma unroll
    for (int n1 = 0; n1 < 16; ++n1) z[n1] = buf[(n1 + 16*q) * 16 + ww];
    dft16<false>(z);                 // over n1 -> k1; h = q + 16*k1
    #pragma unroll
    for (int k1 = 0; k1 < 16; ++k1) B[idxB(t, q + 16*k1, w0 + ww)] = z[k1];
}

// K4 core: one line set through LDS: fwd 256 FFT (radix-16^2) -> psf multiply
// (regs, conj if CONJP) -> inv 256 FFT -> write w<128. Two internal syncs;
// caller syncs between consecutive cores (buf reuse) and after tw init.
template<bool CONJP>
__device__ __forceinline__ void k4_core(
        cplx* __restrict__ B, size_t lineB, int q, int l, cplx* buf, const cplx* tw,
        const float* prv, const float* piv, const cplx* xin) {
    cplx x[16];
    #pragma unroll
    for (int n2 = 0; n2 < 8; ++n2) x[n2] = xin[n2];
    #pragma unroll
    for (int n2 = 8; n2 < 16; ++n2) x[n2] = make_float2(0.f, 0.f);
    dft16<false>(x);                 // over n2 -> k2
    #pragma unroll
    for (int k2 = 1; k2 < 16; ++k2) x[k2] = cmul(x[k2], tw[twp(q * k2)]);
    #pragma unroll
    for (int k2 = 0; k2 < 16; ++k2) buf[l*256 + (q ^ k2) + 16*k2] = x[k2];
    __syncthreads();
    cplx z[16];
    #pragma unroll
    for (int n1 = 0; n1 < 16; ++n1) z[n1] = buf[l*256 + (n1 ^ q) + 16*q];
    dft16<false>(z);                 // z[k1] = X[q + 16*k1]
    #pragma unroll
    for (int k1 = 0; k1 < 16; ++k1) {
        cplx p = make_float2(prv[k1], piv[k1]);
        z[k1] = CONJP ? cmulc(z[k1], p) : cmul(z[k1], p);
    }
    dft16<true>(z);                  // inverse over k1 -> n1
    #pragma unroll
    for (int n1 = 1; n1 < 16; ++n1) z[n1] = cmulc(z[n1], tw[twp(n1 * q)]);
    #pragma unroll
    for (int n1 = 0; n1 < 16; ++n1) buf[l*256 + (n1 ^ q) + 16*q] = z[n1]; // own column
    __syncthreads();
    cplx y[16];
    #pragma unroll
    for (int k2 = 0; k2 < 16; ++k2) y[k2] = buf[l*256 + (q ^ k2) + 16*k2];
    dft16<true>(y);                  // over k2 -> n2; w = q + 16*n2
    #pragma unroll
    for (int n2 = 0; n2 < 8; ++n2) B[lineB + q + 16*n2] = y[n2];
}

// K4: fused w-pass with Hermitian psf pairing done in REGISTERS.
// Block bx<255: pass A = plane kt=bx+1 (psf loaded from HBM), pass B = plane
// 512-kt with mirrored kh lines. Since psf is real:
//   invpsf[512-kt, 256-kh, kw] = conj(invpsf[kt, kh, (256-kw)&255])
// and the mirrored kw lives at lane q'=(16-q)&15, register k1'=15-k1 (q!=0)
// or (16-k1)&15 (q==0) -> pass-B psf comes from 32 __shfl, zero extra HBM.
// Block bx==255 handles the self-conjugate planes 0 and 256 directly.
// psf HBM fetch: 268 MB -> ~135 MB. NOTE: no min-waves clause --
// __launch_bounds__(256,4) capped VGPR at 64 and spilled ~550 MB of scratch
// traffic per dispatch (round-1 regression).
__global__ __launch_bounds__(256) void k4_fftw(
        cplx* __restrict__ B, const float* __restrict__ pr, const float* __restrict__ pim) {
    const int bx = blockIdx.x, kh0 = blockIdx.y * 16;
    const int tid = threadIdx.x, q = tid & 15, l = tid >> 4; // q fast for w-coalescing
    __shared__ cplx buf[16 * 256];
    __shared__ cplx tw[272];
    { float s, c; sincosf(-(2.0f*PI_F/256.0f)*(float)tid, &s, &c); tw[twp(tid)] = make_float2(c, s); }
    const bool last = (bx == 255);
    const int ktA = last ? 0 : bx + 1;           // planes 1..255, and 0
    const int khA = kh0 + l;
    const int ktB = last ? 256 : 512 - ktA;      // planes 257..511, and 256
    const int khB = last ? khA : ((256 - khA) & 255);
    const size_t lineBA = idxB(ktA, khA, 0);
    const size_t lineBB = idxB(ktB, khB, 0);
    const size_t linePA = ((size_t)ktA * 256 + khA) * 256;
    const size_t linePB = ((size_t)ktB * 256 + khB) * 256; // used only when last

    // ---- pass A: psf + data from global ----
    cplx xA[8];
    #pragma unroll
    for (int n2 = 0; n2 < 8; ++n2) xA[n2] = B[lineBA + q + 16*n2];
    float prv[16], piv[16];
    #pragma unroll
    for (int k1 = 0; k1 < 16; ++k1) {
        prv[k1] = pr[linePA + q + 16*k1];
        piv[k1] = pim[linePA + q + 16*k1];
    }
    __syncthreads();                             // tw ready
    k4_core<false>(B, lineBA, q, l, buf, tw, prv, piv, xA);

    // ---- derive pass-B psf from pass-A registers (lane mirror) ----
    float prvB[16], pivB[16];
    if (!last) {
        const int srcLane = (l & 3) * 16 + ((16 - q) & 15); // within the wave
        float sr[16], si[16];
        #pragma unroll
        for (int j = 0; j < 16; ++j) {
            sr[j] = __shfl(prv[j], srcLane, 64);
            si[j] = __shfl(piv[j], srcLane, 64);
        }
        #pragma unroll
        for (int k1 = 0; k1 < 16; ++k1) {
            // kw' = (256 - q - 16*k1) & 255  ->  register index at the mirror lane
            prvB[k1] = (q == 0) ? sr[(16 - k1) & 15] : sr[15 - k1];
            pivB[k1] = (q == 0) ? si[(16 - k1) & 15] : si[15 - k1];
        }
    } else {
        #pragma unroll
        for (int k1 = 0; k1 < 16; ++k1) {
            prvB[k1] = pr[linePB + q + 16*k1];
            pivB[k1] = pim[linePB + q + 16*k1];
        }
    }
    // ---- pass B: plane untouched by ANY pass A (257..511 | 256), lazy load ----
    cplx xB[8];
    #pragma unroll
    for (int n2 = 0; n2 < 8; ++n2) xB[n2] = B[lineBB + q + 16*n2];
    __syncthreads();                             // pass-A buf reads complete
    if (last) k4_core<false>(B, lineBB, q, l, buf, tw, prvB, pivB, xB);
    else      k4_core<true >(B, lineBB, q, l, buf, tw, prvB, pivB, xB);
}

// K5: inverse 256-FFT along h, radix-16^2. Reads all h (natural freq), writes h<128.
__global__ __launch_bounds__(256) void k5_iffth(cplx* __restrict__ B) {
    const int t = blockIdx.x, w0 = blockIdx.y * 16;
    const int tid = threadIdx.x, ww = tid & 15, q = tid >> 4;
    __shared__ cplx buf[256 * 16];
    __shared__ cplx tw[272];
    { float s, c; sincosf(-(2.0f*PI_F/256.0f)*(float)tid, &s, &c); tw[twp(tid)] = make_float2(c, s); }
    cplx x[16];
    #pragma unroll
    for (int k1 = 0; k1 < 16; ++k1) x[k1] = B[idxB(t, q + 16*k1, w0 + ww)]; // q = k2
    dft16<true>(x);                  // over k1 -> n1
    __syncthreads();
    #pragma unroll
    for (int n1 = 1; n1 < 16; ++n1) x[n1] = cmulc(x[n1], tw[twp(n1 * q)]);
    #pragma unroll
    for (int n1 = 0; n1 < 16; ++n1) buf[(n1 + 16*q) * 16 + ww] = x[n1];
    __syncthreads();
    cplx z[16];
    #pragma unroll
    for (int k2 = 0; k2 < 16; ++k2) z[k2] = buf[(q + 16*k2) * 16 + ww]; // q = n1
    dft16<true>(z);                  // over k2 -> n2; h = q + 16*n2
    #pragma unroll
    for (int n2 = 0; n2 < 8; ++n2) B[idxB(t, q + 16*n2, w0 + ww)] = z[n2];
}

// K6': inverse 512-FFT along t fused with mtxi output matvec. Writes d_out only.
__global__ __launch_bounds__(512, 2) void k6_ifftt(
        cplx* __restrict__ B, const float* __restrict__ tv, const int* __restrict__ tc,
        float* __restrict__ out) {
    const int h = blockIdx.x, w0 = blockIdx.y * 16;
    const int tid = threadIdx.x, ww = tid & 15, q = tid >> 4; // q in [0,32)
    __shared__ cplx buf[512 * 17];
    __shared__ cplx tw[512];
    { float s, c; sincosf(-(2.0f*PI_F/512.0f)*(float)tid, &s, &c); tw[tid] = make_float2(c, s); }
    cplx za[2][8];
    for (int hi = 0; hi < 2; ++hi) {
        int m = q + 32*hi, kb = (m >> 3) + 8 * (m & 7);
        #pragma unroll
        for (int s2 = 0; s2 < 8; ++s2) za[hi][s2] = B[idxB(kb + 64*s2, h, w0 + ww)];
    }
    for (int hi = 0; hi < 2; ++hi) {
        int m = q + 32*hi;
        dft8<true>(za[hi]);
        #pragma unroll
        for (int jj = 0; jj < 8; ++jj) buf[(8*m + jj) * 17 + ww] = za[hi][jj];
    }
    __syncthreads();   // covers tw + buf
    for (int hi = 0; hi < 2; ++hi) {
        int u = q + 32*hi, r1 = u >> 3, j = u & 7, base = 64*r1 + j;
        cplx y[8];
        #pragma unroll
        for (int r2 = 0; r2 < 8; ++r2) y[r2] = buf[(base + 8*r2) * 17 + ww];
        #pragma unroll
        for (int r2 = 1; r2 < 8; ++r2) y[r2] = cmulc(y[r2], tw[8 * j * r2]);
        dft8<true>(y);
        #pragma unroll
        for (int p = 0; p < 8; ++p) buf[(base + 8*p) * 17 + ww] = y[p];
    }
    __syncthreads();
    cplx vol[2][4];
    for (int hi = 0; hi < 2; ++hi) {
        int u = q + 32*hi;
        cplx xo[8];
        #pragma unroll
        for (int r = 0; r < 8; ++r) xo[r] = buf[(64*r + u) * 17 + ww];
        #pragma unroll
        for (int r = 1; r < 8; ++r) xo[r] = cmulc(xo[r], tw[u * r]);
        dft8<true>(xo);
        #pragma unroll
        for (int p = 0; p < 4; ++p) vol[hi][p] = xo[p];  // t = u + 64p < 256
    }
    __syncthreads();   // all buf reads done before vol overwrite
    for (int hi = 0; hi < 2; ++hi) {
        int u = q + 32*hi;
        #pragma unroll
        for (int p = 0; p < 4; ++p) buf[(u + 64*p) * 16 + ww] = vol[hi][p];
    }
    __syncthreads();
    // out[m] = sum_j val[m,j] * vol[col[m,j]]  (table broadcast across ww)
    for (int hi = 0; hi < 2; ++hi) {
        int u = q + 32*hi;
        #pragma unroll
        for (int p = 0; p < 4; ++p) {
            int m = u + 64*p;
            cplx acc = make_float2(0.f, 0.f);
            const float4* v4 = (const float4*)(tv + m*8);
            const int4*  c4 = (const int4*)(tc + m*8);
            #pragma unroll
            for (int jj = 0; jj < 2; ++jj) {
                float4 vv = v4[jj]; int4 cc = c4[jj];
                acc = cadd(acc, cax(vv.x, buf[cc.x*16 + ww]));
                acc = cadd(acc, cax(vv.y, buf[cc.y*16 + ww]));
                acc = cadd(acc, cax(vv.z, buf[cc.z*16 + ww]));
                acc = cadd(acc, cax(vv.w, buf[cc.w*16 + ww]));
            }
            out[((size_t)m * 128 + h) * 128 + w0 + ww] = acc.x;
            out[(((size_t)256 + m) * 128 + h) * 128 + w0 + ww] = acc.y;
        }
    }
}

extern "C" void kernel_launch(void* const* d_in, const int* in_sizes, int n_in,
                              void* d_out, int out_size, void* d_ws, size_t ws_size,
                              hipStream_t stream) {
    const float* feat  = (const float*)d_in[0];
    const float* gridz = (const float*)d_in[1];
    const float* mtx   = (const float*)d_in[2];
    const float* mtxi  = (const float*)d_in[3];
    const float* pr    = (const float*)d_in[4];
    const float* pim   = (const float*)d_in[5];
    cplx* B = (cplx*)d_ws; // 512*256*128*8 = 128 MiB
    float* out = (float*)d_out;

    // mtx table in dead region [t=257, h>=128] (dead until k3 writes; consumed by k2')
    float* T1v = (float*)(B + idxB(257, 128, 0));
    int*   T1c = (int*)(T1v + 4096);
    // mtxi table in dead region [t=0, h>=128] (built after k5; consumed by k6')
    float* T2v = (float*)(B + idxB(0, 128, 0));
    int*   T2c = (int*)(T2v + 2048);

    k0_mtx <<<256, 256, 0, stream>>>(mtx, gridz, T1v, T1c);
    k2_fftt<<<dim3(128, 8), 512, 0, stream>>>(feat, T1v, T1c, B);
    k3_ffth<<<dim3(512, 8), 256, 0, stream>>>(B);
    k4_fftw<<<dim3(256, 16), 256, 0, stream>>>(B, pr, pim);
    k5_iffth<<<dim3(512, 8), 256, 0, stream>>>(B);
    k0_mtxi<<<256, 256, 0, stream>>>(mtxi, T2v, T2c);
    k6_ifftt<<<dim3(128, 8), 512, 0, stream>>>(B, T2v, T2c, out);
}

// Round 3
// 470.547 us; speedup vs baseline: 1.6168x; 1.0541x over previous
//
#include <hip/hip_runtime.h>
#include <math.h>

typedef float2 cplx;
#define PI_F 3.14159265358979323846f
#define C8F 0.70710678118654752440f

__device__ __forceinline__ cplx cadd(cplx a, cplx b){ return make_float2(a.x+b.x, a.y+b.y); }
__device__ __forceinline__ cplx csub(cplx a, cplx b){ return make_float2(a.x-b.x, a.y-b.y); }
__device__ __forceinline__ cplx cmul(cplx a, cplx b){ return make_float2(a.x*b.x - a.y*b.y, a.x*b.y + a.y*b.x); }
__device__ __forceinline__ cplx cmulc(cplx a, cplx b){ return make_float2(a.x*b.x + a.y*b.y, a.y*b.x - a.x*b.y); }
__device__ __forceinline__ cplx cax(float s, cplx v){ return make_float2(s*v.x, s*v.y); }

template<bool INV>
__device__ __forceinline__ void dft8(cplx* v) {
    cplx t0 = cadd(v[0], v[4]), u0 = csub(v[0], v[4]);
    cplx t1 = cadd(v[1], v[5]), u1 = csub(v[1], v[5]);
    cplx t2 = cadd(v[2], v[6]), u2 = csub(v[2], v[6]);
    cplx t3 = cadd(v[3], v[7]), u3 = csub(v[3], v[7]);
    if (!INV) {
        u1 = make_float2(C8F*(u1.x + u1.y), C8F*(u1.y - u1.x));
        u2 = make_float2(u2.y, -u2.x);
        u3 = make_float2(C8F*(u3.y - u3.x), -C8F*(u3.x + u3.y));
    } else {
        u1 = make_float2(C8F*(u1.x - u1.y), C8F*(u1.x + u1.y));
        u2 = make_float2(-u2.y, u2.x);
        u3 = make_float2(-C8F*(u3.x + u3.y), C8F*(u3.x - u3.y));
    }
    cplx b0 = cadd(t0,t2), b1 = cadd(t1,t3), b2 = csub(t0,t2), b3 = csub(t1,t3);
    b3 = INV ? make_float2(-b3.y, b3.x) : make_float2(b3.y, -b3.x);
    v[0] = cadd(b0,b1); v[4] = csub(b0,b1); v[2] = cadd(b2,b3); v[6] = csub(b2,b3);
    cplx c0 = cadd(u0,u2), c1 = cadd(u1,u3), c2 = csub(u0,u2), c3 = csub(u1,u3);
    c3 = INV ? make_float2(-c3.y, c3.x) : make_float2(c3.y, -c3.x);
    v[1] = cadd(c0,c1); v[5] = csub(c0,c1); v[3] = cadd(c2,c3); v[7] = csub(c2,c3);
}

template<bool INV>
__device__ __forceinline__ void dft4(cplx* v) {
    cplx b0 = cadd(v[0], v[2]), b2 = csub(v[0], v[2]);
    cplx b1 = cadd(v[1], v[3]), b3 = csub(v[1], v[3]);
    b3 = INV ? make_float2(-b3.y, b3.x) : make_float2(b3.y, -b3.x);
    v[0] = cadd(b0,b1); v[2] = csub(b0,b1); v[1] = cadd(b2,b3); v[3] = csub(b2,b3);
}

// 16-point DFT, natural in/out. X[c+4d] = sum_a W16^{ac} W4^{ad} (sum_b x[a+4b] W4^{bc})
template<bool INV>
__device__ __forceinline__ void dft16(cplx* v) {
    #pragma unroll
    for (int a = 0; a < 4; ++a) {
        cplx t[4] = { v[a], v[a+4], v[a+8], v[a+12] };
        dft4<INV>(t);
        v[a] = t[0]; v[a+4] = t[1]; v[a+8] = t[2]; v[a+12] = t[3];
    }
    const float C1 = 0.92387953251128674f, S1 = 0.38268343236508978f, R2 = 0.70710678118654752f;
    #define TWX(idx, CR, CI) v[idx] = cmul(v[idx], make_float2(CR, INV ? -(CI) : (CI)))
    TWX(1+4*1,  C1, -S1);   // W16^1
    TWX(1+4*2,  R2, -R2);   // W16^2
    TWX(1+4*3,  S1, -C1);   // W16^3
    TWX(2+4*1,  R2, -R2);   // W16^2
    TWX(2+4*2, 0.f, -1.f);  // W16^4
    TWX(2+4*3, -R2, -R2);   // W16^6
    TWX(3+4*1,  S1, -C1);   // W16^3
    TWX(3+4*2, -R2, -R2);   // W16^6
    TWX(3+4*3, -C1,  S1);   // W16^9
    #undef TWX
    cplx o[16];
    #pragma unroll
    for (int c = 0; c < 4; ++c) {
        cplx t[4] = { v[4*c+0], v[4*c+1], v[4*c+2], v[4*c+3] };
        dft4<INV>(t);
        o[c] = t[0]; o[c+4] = t[1]; o[c+8] = t[2]; o[c+12] = t[3];
    }
    #pragma unroll
    for (int i = 0; i < 16; ++i) v[i] = o[i];
}

// swizzled twiddle-table index (breaks bank collisions for strided products)
__device__ __forceinline__ int twp(int i){ return i + (i >> 4); }

// B: [512 t][256 h][128 w] cplx = 128 MiB (all of d_ws).
__host__ __device__ __forceinline__ size_t idxB(int t, int h, int w) {
    return ((size_t)t * 256 + h) * 128 + w;
}

// K0a: compact row m of (mtx * gridz^4) into <=16 (val,col) pairs (banded).
__global__ __launch_bounds__(256) void k0_mtx(
        const float* __restrict__ mtx, const float* __restrict__ gridz,
        float* __restrict__ tv, int* __restrict__ tc) {
    int m = blockIdx.x, t = threadIdx.x;
    __shared__ float rv[256];
    float g = gridz[t]; float g2 = g * g;
    rv[t] = mtx[m * 256 + t] * (g2 * g2);
    __syncthreads();
    if (t == 0) {
        int cnt = 0;
        for (int k = 0; k < 256 && cnt < 16; ++k)
            if (rv[k] != 0.f) { tv[m*16 + cnt] = rv[k]; tc[m*16 + cnt] = k; ++cnt; }
        for (; cnt < 16; ++cnt) { tv[m*16 + cnt] = 0.f; tc[m*16 + cnt] = 0; }
    }
}

// K0b: compact row m of mtxi into <=8 (val,col) pairs.
// Global ifft normalization 1/(512*256*256) = 2^-25 folded in (exact in fp32).
__global__ __launch_bounds__(256) void k0_mtxi(
        const float* __restrict__ mtxi, float* __restrict__ tv, int* __restrict__ tc) {
    int m = blockIdx.x, t = threadIdx.x;
    const float S = 2.9802322387695312e-08f; // 1/2^25, exact
    __shared__ float rv[256];
    rv[t] = mtxi[m * 256 + t];
    __syncthreads();
    if (t == 0) {
        int cnt = 0;
        for (int k = 0; k < 256 && cnt < 8; ++k)
            if (rv[k] != 0.f) { tv[m*8 + cnt] = rv[k] * S; tc[m*8 + cnt] = k; ++cnt; }
        for (; cnt < 8; ++cnt) { tv[m*8 + cnt] = 0.f; tc[m*8 + cnt] = 0; }
    }
}

// K2': fused resample + forward 512-FFT along t. Reads feat, writes B[all t, h<128].
__global__ __launch_bounds__(512, 2) void k2_fftt(
        const float* __restrict__ feat, const float* __restrict__ tv,
        const int* __restrict__ tc, cplx* __restrict__ B) {
    const int h = blockIdx.x, w0 = blockIdx.y * 16;
    const int tid = threadIdx.x, ww = tid & 15, q = tid >> 4; // q in [0,32)
    __shared__ cplx buf[512 * 17];
    __shared__ cplx tw[512];
    { float s, c; sincosf(-(2.0f*PI_F/512.0f)*(float)tid, &s, &c); tw[tid] = make_float2(c, s); }
    // stage feat (both channels packed re+i*im) into LDS: f2[t*16+ww], t<256
    cplx* f2 = buf;
    for (int idx = tid; idx < 4096; idx += 512) {
        int t = idx >> 4, w = idx & 15;
        size_t o = ((size_t)t * 128 + h) * 128 + w0 + w;
        f2[idx] = make_float2(feat[o], feat[o + 4194304]);
    }
    __syncthreads();
    // sparse matvec: A[m] = sum_j val[m,j] * f2[col[m,j]]  (table broadcast across ww)
    cplx xa[2][8];
    for (int hi = 0; hi < 2; ++hi) {
        int u = q + 32*hi;
        #pragma unroll
        for (int p = 0; p < 8; ++p) {
            if (p < 4) {
                int m = u + 64*p;
                cplx acc = make_float2(0.f, 0.f);
                const float4* v4 = (const float4*)(tv + m*16);
                const int4*  c4 = (const int4*)(tc + m*16);
                #pragma unroll
                for (int jj = 0; jj < 4; ++jj) {
                    float4 vv = v4[jj]; int4 cc = c4[jj];
                    acc = cadd(acc, cax(vv.x, f2[cc.x*16 + ww]));
                    acc = cadd(acc, cax(vv.y, f2[cc.y*16 + ww]));
                    acc = cadd(acc, cax(vv.z, f2[cc.z*16 + ww]));
                    acc = cadd(acc, cax(vv.w, f2[cc.w*16 + ww]));
                }
                xa[hi][p] = acc;
            } else xa[hi][p] = make_float2(0.f, 0.f);
        }
    }
    dft8<false>(xa[0]); dft8<false>(xa[1]);
    __syncthreads();   // all f2 reads done before stage-A overwrites
    for (int hi = 0; hi < 2; ++hi) {
        int u = q + 32*hi;
        #pragma unroll
        for (int r = 1; r < 8; ++r) xa[hi][r] = cmul(xa[hi][r], tw[u * r]);
        #pragma unroll
        for (int r = 0; r < 8; ++r) buf[(64*r + u) * 17 + ww] = xa[hi][r];
    }
    __syncthreads();
    for (int hi = 0; hi < 2; ++hi) {
        int u = q + 32*hi, r1 = u >> 3, j = u & 7, base = 64*r1 + j;
        cplx y[8];
        #pragma unroll
        for (int p = 0; p < 8; ++p) y[p] = buf[(base + 8*p) * 17 + ww];
        dft8<false>(y);
        #pragma unroll
        for (int r2 = 1; r2 < 8; ++r2) y[r2] = cmul(y[r2], tw[8 * j * r2]);
        #pragma unroll
        for (int r2 = 0; r2 < 8; ++r2) buf[(base + 8*r2) * 17 + ww] = y[r2];
    }
    __syncthreads();
    for (int hi = 0; hi < 2; ++hi) {
        int m = q + 32*hi;
        cplx z[8];
        #pragma unroll
        for (int r = 0; r < 8; ++r) z[r] = buf[(8*m + r) * 17 + ww];
        dft8<false>(z);
        int kb = (m >> 3) + 8 * (m & 7);
        #pragma unroll
        for (int s2 = 0; s2 < 8; ++s2)
            B[idxB(kb + 64*s2, h, w0 + ww)] = z[s2];
    }
}

// K3: forward 256-FFT along h, radix-16^2, 1 LDS exchange. Reads h<128, writes all h.
__global__ __launch_bounds__(256) void k3_ffth(cplx* __restrict__ B) {
    const int t = blockIdx.x, w0 = blockIdx.y * 16;
    const int tid = threadIdx.x, ww = tid & 15, q = tid >> 4; // q in [0,16)
    __shared__ cplx buf[256 * 16];
    __shared__ cplx tw[272];
    { float s, c; sincosf(-(2.0f*PI_F/256.0f)*(float)tid, &s, &c); tw[twp(tid)] = make_float2(c, s); }
    cplx x[16];
    #pragma unroll
    for (int n2 = 0; n2 < 8; ++n2) x[n2] = B[idxB(t, q + 16*n2, w0 + ww)];
    #pragma unroll
    for (int n2 = 8; n2 < 16; ++n2) x[n2] = make_float2(0.f, 0.f);
    dft16<false>(x);                 // over n2 -> k2
    __syncthreads();                 // tw ready
    #pragma unroll
    for (int k2 = 1; k2 < 16; ++k2) x[k2] = cmul(x[k2], tw[twp(q * k2)]);
    #pragma unroll
    for (int k2 = 0; k2 < 16; ++k2) buf[(q + 16*k2) * 16 + ww] = x[k2];
    __syncthreads();
    cplx z[16];
    #pragma unroll
    for (int n1 = 0; n1 < 16; ++n1) z[n1] = buf[(n1 + 16*q) * 16 + ww];
    dft16<false>(z);                 // over n1 -> k1; h = q + 16*k1
    #pragma unroll
    for (int k1 = 0; k1 < 16; ++k1) B[idxB(t, q + 16*k1, w0 + ww)] = z[k1];
}

// K4: fused w-pass with SPATIAL Hermitian psf pairing (round-2's temporal pairing
// serialized the block and cost 15%). Block (bx, by): rows l<8 process plane
// ktA=bx+1 at kh=by*8+l (psf row fetched from HBM); rows l>=8 process plane
// 512-ktA at the mirrored kh=(256-khA)&255, reading the SAME psf row reversed
// (invpsf[512-kt,256-kh,kw] = conj(invpsf[kt,kh,(256-kw)&255]), psf real) ->
// concurrent L1/L2 hits, no serialization, no shuffles. Block bx==255 handles
// the self-conjugate planes 0 (l<8) and 256 (l>=8) with direct psf reads.
// conj flag is wave-uniform (waves 0-1 = half A, waves 2-3 = half B).
// psf HBM fetch stays halved (~134 MB); grid back to 8192 blocks, 1 pass/thread.
__global__ __launch_bounds__(256) void k4_fftw(
        cplx* __restrict__ B, const float* __restrict__ pr, const float* __restrict__ pim) {
    const int bx = blockIdx.x, kh0 = blockIdx.y * 8;
    const int tid = threadIdx.x, q = tid & 15, l = tid >> 4; // q fast for w-coalescing
    const int lh = l & 7;
    const bool halfB = (l >= 8);
    __shared__ cplx buf[16 * 256];
    __shared__ cplx tw[272];
    { float s, c; sincosf(-(2.0f*PI_F/256.0f)*(float)tid, &s, &c); tw[twp(tid)] = make_float2(c, s); }
    const bool self = (bx == 255);
    const int ktA = self ? 0 : bx + 1;            // A planes: 1..255, and 0
    const int khA = kh0 + lh;                     // A row (also the psf source row)
    const int kt  = halfB ? (self ? 256 : 512 - ktA) : ktA;
    const int kh  = (halfB && !self) ? ((256 - khA) & 255) : khA;
    const bool conj = halfB && !self;
    const size_t lineB = idxB(kt, kh, 0);
    const size_t lineP = ((size_t)(halfB && self ? 256 : ktA) * 256 + khA) * 256;

    cplx x[16];
    #pragma unroll
    for (int n2 = 0; n2 < 8; ++n2) x[n2] = B[lineB + q + 16*n2];
    #pragma unroll
    for (int n2 = 8; n2 < 16; ++n2) x[n2] = make_float2(0.f, 0.f);
    float prv[16], piv[16];
    #pragma unroll
    for (int k1 = 0; k1 < 16; ++k1) {
        int kw = q + 16*k1;
        int ip = conj ? ((256 - kw) & 255) : kw;
        prv[k1] = pr[lineP + ip];
        piv[k1] = conj ? -pim[lineP + ip] : pim[lineP + ip]; // fold conj into load
    }
    dft16<false>(x);                 // over n2 -> k2
    __syncthreads();                 // tw ready
    #pragma unroll
    for (int k2 = 1; k2 < 16; ++k2) x[k2] = cmul(x[k2], tw[twp(q * k2)]);
    #pragma unroll
    for (int k2 = 0; k2 < 16; ++k2) buf[l*256 + (q ^ k2) + 16*k2] = x[k2];
    __syncthreads();
    cplx z[16];
    #pragma unroll
    for (int n1 = 0; n1 < 16; ++n1) z[n1] = buf[l*256 + (n1 ^ q) + 16*q];
    dft16<false>(z);                 // z[k1] = X[q + 16*k1]
    #pragma unroll
    for (int k1 = 0; k1 < 16; ++k1)
        z[k1] = cmul(z[k1], make_float2(prv[k1], piv[k1]));
    dft16<true>(z);                  // inverse over k1 -> n1
    #pragma unroll
    for (int n1 = 1; n1 < 16; ++n1) z[n1] = cmulc(z[n1], tw[twp(n1 * q)]);
    #pragma unroll
    for (int n1 = 0; n1 < 16; ++n1) buf[l*256 + (n1 ^ q) + 16*q] = z[n1]; // own column
    __syncthreads();
    cplx y[16];
    #pragma unroll
    for (int k2 = 0; k2 < 16; ++k2) y[k2] = buf[l*256 + (q ^ k2) + 16*k2];
    dft16<true>(y);                  // over k2 -> n2; w = q + 16*n2
    #pragma unroll
    for (int n2 = 0; n2 < 8; ++n2) B[lineB + q + 16*n2] = y[n2];
}

// K5: inverse 256-FFT along h, radix-16^2. Reads all h (natural freq), writes h<128.
__global__ __launch_bounds__(256) void k5_iffth(cplx* __restrict__ B) {
    const int t = blockIdx.x, w0 = blockIdx.y * 16;
    const int tid = threadIdx.x, ww = tid & 15, q = tid >> 4;
    __shared__ cplx buf[256 * 16];
    __shared__ cplx tw[272];
    { float s, c; sincosf(-(2.0f*PI_F/256.0f)*(float)tid, &s, &c); tw[twp(tid)] = make_float2(c, s); }
    cplx x[16];
    #pragma unroll
    for (int k1 = 0; k1 < 16; ++k1) x[k1] = B[idxB(t, q + 16*k1, w0 + ww)]; // q = k2
    dft16<true>(x);                  // over k1 -> n1
    __syncthreads();
    #pragma unroll
    for (int n1 = 1; n1 < 16; ++n1) x[n1] = cmulc(x[n1], tw[twp(n1 * q)]);
    #pragma unroll
    for (int n1 = 0; n1 < 16; ++n1) buf[(n1 + 16*q) * 16 + ww] = x[n1];
    __syncthreads();
    cplx z[16];
    #pragma unroll
    for (int k2 = 0; k2 < 16; ++k2) z[k2] = buf[(q + 16*k2) * 16 + ww]; // q = n1
    dft16<true>(z);                  // over k2 -> n2; h = q + 16*n2
    #pragma unroll
    for (int n2 = 0; n2 < 8; ++n2) B[idxB(t, q + 16*n2, w0 + ww)] = z[n2];
}

// K6': inverse 512-FFT along t fused with mtxi output matvec. Writes d_out only.
__global__ __launch_bounds__(512, 2) void k6_ifftt(
        cplx* __restrict__ B, const float* __restrict__ tv, const int* __restrict__ tc,
        float* __restrict__ out) {
    const int h = blockIdx.x, w0 = blockIdx.y * 16;
    const int tid = threadIdx.x, ww = tid & 15, q = tid >> 4; // q in [0,32)
    __shared__ cplx buf[512 * 17];
    __shared__ cplx tw[512];
    { float s, c; sincosf(-(2.0f*PI_F/512.0f)*(float)tid, &s, &c); tw[tid] = make_float2(c, s); }
    cplx za[2][8];
    for (int hi = 0; hi < 2; ++hi) {
        int m = q + 32*hi, kb = (m >> 3) + 8 * (m & 7);
        #pragma unroll
        for (int s2 = 0; s2 < 8; ++s2) za[hi][s2] = B[idxB(kb + 64*s2, h, w0 + ww)];
    }
    for (int hi = 0; hi < 2; ++hi) {
        int m = q + 32*hi;
        dft8<true>(za[hi]);
        #pragma unroll
        for (int jj = 0; jj < 8; ++jj) buf[(8*m + jj) * 17 + ww] = za[hi][jj];
    }
    __syncthreads();   // covers tw + buf
    for (int hi = 0; hi < 2; ++hi) {
        int u = q + 32*hi, r1 = u >> 3, j = u & 7, base = 64*r1 + j;
        cplx y[8];
        #pragma unroll
        for (int r2 = 0; r2 < 8; ++r2) y[r2] = buf[(base + 8*r2) * 17 + ww];
        #pragma unroll
        for (int r2 = 1; r2 < 8; ++r2) y[r2] = cmulc(y[r2], tw[8 * j * r2]);
        dft8<true>(y);
        #pragma unroll
        for (int p = 0; p < 8; ++p) buf[(base + 8*p) * 17 + ww] = y[p];
    }
    __syncthreads();
    cplx vol[2][4];
    for (int hi = 0; hi < 2; ++hi) {
        int u = q + 32*hi;
        cplx xo[8];
        #pragma unroll
        for (int r = 0; r < 8; ++r) xo[r] = buf[(64*r + u) * 17 + ww];
        #pragma unroll
        for (int r = 1; r < 8; ++r) xo[r] = cmulc(xo[r], tw[u * r]);
        dft8<true>(xo);
        #pragma unroll
        for (int p = 0; p < 4; ++p) vol[hi][p] = xo[p];  // t = u + 64p < 256
    }
    __syncthreads();   // all buf reads done before vol overwrite
    for (int hi = 0; hi < 2; ++hi) {
        int u = q + 32*hi;
        #pragma unroll
        for (int p = 0; p < 4; ++p) buf[(u + 64*p) * 16 + ww] = vol[hi][p];
    }
    __syncthreads();
    // out[m] = sum_j val[m,j] * vol[col[m,j]]  (table broadcast across ww)
    for (int hi = 0; hi < 2; ++hi) {
        int u = q + 32*hi;
        #pragma unroll
        for (int p = 0; p < 4; ++p) {
            int m = u + 64*p;
            cplx acc = make_float2(0.f, 0.f);
            const float4* v4 = (const float4*)(tv + m*8);
            const int4*  c4 = (const int4*)(tc + m*8);
            #pragma unroll
            for (int jj = 0; jj < 2; ++jj) {
                float4 vv = v4[jj]; int4 cc = c4[jj];
                acc = cadd(acc, cax(vv.x, buf[cc.x*16 + ww]));
                acc = cadd(acc, cax(vv.y, buf[cc.y*16 + ww]));
                acc = cadd(acc, cax(vv.z, buf[cc.z*16 + ww]));
                acc = cadd(acc, cax(vv.w, buf[cc.w*16 + ww]));
            }
            out[((size_t)m * 128 + h) * 128 + w0 + ww] = acc.x;
            out[(((size_t)256 + m) * 128 + h) * 128 + w0 + ww] = acc.y;
        }
    }
}

extern "C" void kernel_launch(void* const* d_in, const int* in_sizes, int n_in,
                              void* d_out, int out_size, void* d_ws, size_t ws_size,
                              hipStream_t stream) {
    const float* feat  = (const float*)d_in[0];
    const float* gridz = (const float*)d_in[1];
    const float* mtx   = (const float*)d_in[2];
    const float* mtxi  = (const float*)d_in[3];
    const float* pr    = (const float*)d_in[4];
    const float* pim   = (const float*)d_in[5];
    cplx* B = (cplx*)d_ws; // 512*256*128*8 = 128 MiB
    float* out = (float*)d_out;

    // mtx table in dead region [t=257, h>=128] (dead until k3 writes; consumed by k2')
    float* T1v = (float*)(B + idxB(257, 128, 0));
    int*   T1c = (int*)(T1v + 4096);
    // mtxi table in dead region [t=0, h>=128] (built after k5; consumed by k6')
    float* T2v = (float*)(B + idxB(0, 128, 0));
    int*   T2c = (int*)(T2v + 2048);

    k0_mtx <<<256, 256, 0, stream>>>(mtx, gridz, T1v, T1c);
    k2_fftt<<<dim3(128, 8), 512, 0, stream>>>(feat, T1v, T1c, B);
    k3_ffth<<<dim3(512, 8), 256, 0, stream>>>(B);
    k4_fftw<<<dim3(256, 32), 256, 0, stream>>>(B, pr, pim);
    k5_iffth<<<dim3(512, 8), 256, 0, stream>>>(B);
    k0_mtxi<<<256, 256, 0, stream>>>(mtxi, T2v, T2c);
    k6_ifftt<<<dim3(128, 8), 512, 0, stream>>>(B, T2v, T2c, out);
}